// Round 10
// baseline (245.612 us; speedup 1.0000x reference)
//
#include <hip/hip_runtime.h>
#include <hip/hip_fp16.h>

#define F_IN 128
#define C_DIM 300
#define NEG_SLOPE 0.2f
#define NCT  38           // col-tile count for Bp (608 cols: 0-299=L, 304-603=R, rest pad)
#define CTH  10           // col-tiles per gemm block (4-way column split; ct>=38 skipped)
#define CH   8            // edges per chunk in gat_gather
#define NPB  256          // blocks for bucket passes (and matrix stride)

typedef _Float16 half8 __attribute__((ext_vector_type(8)));
typedef _Float16 half4 __attribute__((ext_vector_type(4)));
typedef _Float16 h2    __attribute__((ext_vector_type(2)));
typedef float    f32x4 __attribute__((ext_vector_type(4)));
typedef float    f32x2 __attribute__((ext_vector_type(2)));

__device__ inline h2 as_h2(unsigned u) { union { unsigned u; h2 h; } c; c.u = u; return c.h; }
__device__ inline unsigned as_u(h2 h)  { union { unsigned u; h2 h; } c; c.h = h; return c.u; }
__device__ inline f32x2 upv(unsigned u) {
    h2 h = as_h2(u);
    f32x2 r; r.x = (float)h.x; r.y = (float)h.y; return r;
}

#if __has_builtin(__builtin_amdgcn_fdot2)
__device__ inline float fdot2w(h2 a, h2 b, float c) {
    return __builtin_amdgcn_fdot2(a, b, c, false);
}
#else
__device__ inline float fdot2w(h2 a, h2 b, float c) {
    return fmaf((float)a.y, (float)b.y, fmaf((float)a.x, (float)b.x, c));
}
#endif

// ---------- K0+P1 merged: convert_w + bucket_count (512 thr = 8 waves/CU) ----------
__global__ __launch_bounds__(512) void conv_count(
    const float* __restrict__ Wl, const float* __restrict__ Wr,
    _Float16* __restrict__ Bp,
    const int* __restrict__ dst, unsigned* __restrict__ bcnt, int nE, int chunk4)
{
    __shared__ unsigned cnt[256];
    const int b = blockIdx.x, t = threadIdx.x;

    // convert_w: 608*128 = 77824 elems over 131072 threads (single strided step)
    {
        int idx = b * 512 + t;
        if (idx < 608 * F_IN) {
            int nn = idx % 608;
            int k  = idx / 608;
            float v = 0.f;
            if (nn < 300)                   v = Wl[k * C_DIM + nn];
            else if (nn >= 304 && nn < 604) v = Wr[k * C_DIM + (nn - 304)];
            int ct = nn >> 4, n16 = nn & 15;
            int kr = k & 31,  ks  = k >> 5;
            int lane = ((kr >> 3) << 4) | n16;
            int j = k & 7;
            Bp[((((ct * 4 + ks) * 64) + lane) << 3) | j] = (_Float16)v;
        }
    }

    if (t < 256) cnt[t] = 0;
    __syncthreads();
    const int4* dst4 = reinterpret_cast<const int4*>(dst);
    const int total4 = (nE + 3) >> 2;
    const int lo = b * chunk4;
    const int hi = min(total4, lo + chunk4);
    for (int i = lo + t; i < hi; i += 512) {
        int4 d = dst4[i];
        int e = i * 4;
        if (e + 3 < nE) {
            atomicAdd(&cnt[d.x >> 8], 1u);
            atomicAdd(&cnt[d.y >> 8], 1u);
            atomicAdd(&cnt[d.z >> 8], 1u);
            atomicAdd(&cnt[d.w >> 8], 1u);
        } else {
            if (e < nE)     atomicAdd(&cnt[d.x >> 8], 1u);
            if (e + 1 < nE) atomicAdd(&cnt[d.y >> 8], 1u);
            if (e + 2 < nE) atomicAdd(&cnt[d.z >> 8], 1u);
        }
    }
    __syncthreads();
    if (t < 256) bcnt[t * NPB + b] = cnt[t];
}

// ---------- P2: exclusive scan of the full 65536-entry matrix in ONE block ----------
// replaces scan_part + scan_final (two ~64-block dispatches, mostly launch floor).
// 1024 threads x 64 contiguous entries each; ~512 KB r+w on one CU.
__global__ __launch_bounds__(1024) void scan_all(
    const unsigned* __restrict__ bcnt, unsigned* __restrict__ boff, int M)
{
    __shared__ unsigned s[1024];
    const int t = threadIdx.x;
    unsigned loc[64];
    unsigned sum = 0;
    const uint4* in4 = reinterpret_cast<const uint4*>(bcnt) + (size_t)t * 16;
    #pragma unroll
    for (int j = 0; j < 16; ++j) {
        uint4 v = in4[j];
        loc[j * 4 + 0] = v.x; loc[j * 4 + 1] = v.y;
        loc[j * 4 + 2] = v.z; loc[j * 4 + 3] = v.w;
        sum += v.x + v.y + v.z + v.w;
    }
    s[t] = sum;
    __syncthreads();
    for (int off = 1; off < 1024; off <<= 1) {
        unsigned u = (t >= off) ? s[t - off] : 0u;
        __syncthreads();
        if (t >= off) s[t] += u;
        __syncthreads();
    }
    unsigned run = (t > 0) ? s[t - 1] : 0u;
    uint4* out4 = reinterpret_cast<uint4*>(boff) + (size_t)t * 16;
    #pragma unroll
    for (int j = 0; j < 16; ++j) {
        uint4 o;
        o.x = run; run += loc[j * 4 + 0];
        o.y = run; run += loc[j * 4 + 1];
        o.z = run; run += loc[j * 4 + 2];
        o.w = run; run += loc[j * 4 + 3];
        out4[j] = o;
    }
    if (t == 1023) boff[M] = run;
}

// P3: scatter edges into bucket-partitioned ebuf; packed u32/edge; int4 reads.
__global__ __launch_bounds__(512) void partition_edges(
    const int* __restrict__ src, const int* __restrict__ dst,
    const unsigned* __restrict__ boff,
    unsigned* __restrict__ ebuf, int nE, int chunk4)
{
    __shared__ unsigned cur[256];
    const int b = blockIdx.x, t = threadIdx.x;
    if (t < 256) cur[t] = boff[t * NPB + b];
    __syncthreads();
    const int4* dst4 = reinterpret_cast<const int4*>(dst);
    const int4* src4 = reinterpret_cast<const int4*>(src);
    const int total4 = (nE + 3) >> 2;
    const int lo = b * chunk4;
    const int hi = min(total4, lo + chunk4);
    for (int i = lo + t; i < hi; i += 512) {
        int4 d = dst4[i];
        int4 s = src4[i];
        int e = i * 4;
        int dv[4] = {d.x, d.y, d.z, d.w};
        int sv[4] = {s.x, s.y, s.z, s.w};
        #pragma unroll
        for (int j = 0; j < 4; ++j) {
            if (e + j < nE) {
                unsigned p = atomicAdd(&cur[dv[j] >> 8], 1u);
                ebuf[p] = (unsigned)sv[j] | ((unsigned)(dv[j] & 255) << 16);
            }
        }
    }
}

// P4: one block per bucket, 512 threads: LDS count + guarded LDS scan -> offs,
// LDS-cursor scatter.
__global__ __launch_bounds__(512) void bucket_csr(
    const unsigned* __restrict__ ebuf, const unsigned* __restrict__ boff,
    unsigned* __restrict__ offs, int* __restrict__ csr_src, int n, int nE, int nb)
{
    __shared__ unsigned cnt[256];
    __shared__ unsigned s[256];
    __shared__ unsigned cur[256];
    const int bk = blockIdx.x;
    const int t  = threadIdx.x;
    const unsigned bstart = boff[(unsigned)bk * NPB];
    const unsigned bend   = boff[(unsigned)(bk + 1) * NPB];
    if (t < 256) cnt[t] = 0;
    __syncthreads();
    for (unsigned i = bstart + t; i < bend; i += 512)
        atomicAdd(&cnt[(ebuf[i] >> 16) & 255], 1u);
    __syncthreads();
    unsigned v = (t < 256) ? cnt[t] : 0u;
    if (t < 256) s[t] = v;
    __syncthreads();
    for (int off = 1; off < 256; off <<= 1) {
        unsigned u = (t >= off && t < 256) ? s[t - off] : 0u;
        __syncthreads();
        if (t >= off && t < 256) s[t] += u;
        __syncthreads();
    }
    if (t < 256) {
        const unsigned excl = s[t] - v;
        const int node = (bk << 8) + t;
        if (node <= n) offs[node] = bstart + excl;
        cur[t] = bstart + excl;
    }
    if (t == 0 && bk == nb - 1 && (n & 255) == 0) offs[n] = (unsigned)nE;
    __syncthreads();
    for (unsigned i = bstart + t; i < bend; i += 512) {
        unsigned e = ebuf[i];
        unsigned p = atomicAdd(&cur[(e >> 16) & 255], 1u);
        csr_src[p] = (int)(e & 0xFFFFu);
    }
}

// ---------- K1: dual GEMM via f16 MFMA ----------
// 64-row blocks, 4-way column split (3128 blocks) + next-ct B prefetch.
// TLP is the lever here (round-6 PMC: all pipes idle at 782 blocks; round-7 2-way
// split verified -15us). ct >= 38 tiles are skipped (pad).
__global__ __launch_bounds__(256) void gemm_xlxr(
    const float* __restrict__ x, const _Float16* __restrict__ Bp,
    const float* __restrict__ bl, const float* __restrict__ br,
    _Float16* __restrict__ xlh, _Float16* __restrict__ xrh, int n)
{
    __shared__ __align__(16) _Float16 xs[64][136];
    const int rg  = blockIdx.x >> 2;
    const int cs  = blockIdx.x & 3;
    const int rb0 = rg * 64;
    const int t   = threadIdx.x;

    #pragma unroll
    for (int i = 0; i < 8; ++i) {
        int flat = (i * 256 + t) * 4;
        int r = flat >> 7;
        int k = flat & 127;
        int gr = rb0 + r;
        if (gr >= n) gr = n - 1;
        float4 v = *reinterpret_cast<const float4*>(x + (size_t)gr * F_IN + k);
        half4 h = { (_Float16)v.x, (_Float16)v.y, (_Float16)v.z, (_Float16)v.w };
        *reinterpret_cast<half4*>(&xs[r][k]) = h;
    }
    __syncthreads();

    const int w    = t >> 6;
    const int lane = t & 63;
    const int m    = lane & 15;
    const int quad = lane >> 4;

    half8 a[4];
    #pragma unroll
    for (int ks = 0; ks < 4; ++ks)
        a[ks] = *reinterpret_cast<const half8*>(&xs[w * 16 + m][ks * 32 + quad * 8]);

    const int rbase = rb0 + w * 16 + quad * 4;
    const int ct0   = cs * CTH;
    const int ctend = min(ct0 + CTH, NCT);

    const half8* bp = reinterpret_cast<const half8*>(Bp);
    half8 bc0 = bp[((size_t)(ct0 * 4 + 0) * 64) + lane];
    half8 bc1 = bp[((size_t)(ct0 * 4 + 1) * 64) + lane];
    half8 bc2 = bp[((size_t)(ct0 * 4 + 2) * 64) + lane];
    half8 bc3 = bp[((size_t)(ct0 * 4 + 3) * 64) + lane];

    for (int ct = ct0; ct < ctend; ++ct) {
        const int ctn = (ct + 1 < ctend) ? ct + 1 : ct;
        half8 bn0 = bp[((size_t)(ctn * 4 + 0) * 64) + lane];
        half8 bn1 = bp[((size_t)(ctn * 4 + 1) * 64) + lane];
        half8 bn2 = bp[((size_t)(ctn * 4 + 2) * 64) + lane];
        half8 bn3 = bp[((size_t)(ctn * 4 + 3) * 64) + lane];

        f32x4 acc = {0.f, 0.f, 0.f, 0.f};
        acc = __builtin_amdgcn_mfma_f32_16x16x32_f16(a[0], bc0, acc, 0, 0, 0);
        acc = __builtin_amdgcn_mfma_f32_16x16x32_f16(a[1], bc1, acc, 0, 0, 0);
        acc = __builtin_amdgcn_mfma_f32_16x16x32_f16(a[2], bc2, acc, 0, 0, 0);
        acc = __builtin_amdgcn_mfma_f32_16x16x32_f16(a[3], bc3, acc, 0, 0, 0);

        int col = ct * 16 + m;
        int isL = (col < 300);
        int isR = (col >= 304 && col < 604);
        if (isL | isR) {
            float bv = isL ? bl[col] : br[col - 304];
            _Float16* tab = isL ? (xlh + col) : (xrh + (col - 304));
            #pragma unroll
            for (int reg = 0; reg < 4; ++reg) {
                int row = rbase + reg;
                if (row < n)
                    tab[(size_t)row * C_DIM] = (_Float16)(acc[reg] + bv);
            }
        }
        bc0 = bn0; bc1 = bn1; bc2 = bn2; bc3 = bn3;
    }
}

// ---------- K2: fused per-node gather, chunked softmax (8 edges/iter) ----------
// 44-VGPR structure + next-chunk csr_src prefetch. FROZEN (rounds 2/4/5/7/9 verified;
// at pattern-BW floor: 276 MB @ ~3.15 TB/s).
__global__ __launch_bounds__(256) void gat_gather(
    const int* __restrict__ csr_src, const unsigned* __restrict__ offs,
    const _Float16* __restrict__ xlh, const _Float16* __restrict__ xrh,
    const float* __restrict__ att, const float* __restrict__ bias,
    const float* __restrict__ lw, const float* __restrict__ lb,
    float* __restrict__ y, int n)
{
    __shared__ __align__(16) float lds[4 * 560];   // per wave: part[8][68]
    float* part = lds + (threadIdx.x >> 6) * 560;

    const int wid  = (blockIdx.x * blockDim.x + threadIdx.x) >> 6;
    const int lane = threadIdx.x & 63;
    if (wid >= n) return;

    const int l2   = 2 * lane;
    const bool has2 = (lane < 22);
    const int t8   = lane & 7;
    const int o    = lane >> 3;
    const int byteoff = lane * 4;

    const _Float16* xrrow = xrh + (size_t)wid * C_DIM;
    h2 xr0 = *(const h2*)(xrrow + l2);
    h2 xr1 = *(const h2*)(xrrow + 128 + l2);
    h2 xr2 = {(_Float16)0, (_Float16)0};
    if (has2) xr2 = *(const h2*)(xrrow + 256 + l2);

    h2 a06[3], a04[3];
    #pragma unroll
    for (int k = 0; k < 3; ++k) {
        int c = 128 * k + l2;
        float ax = (c < C_DIM) ? att[c] : 0.f;
        float ay = (c + 1 < C_DIM) ? att[c + 1] : 0.f;
        a06[k].x = (_Float16)(0.6f * ax); a06[k].y = (_Float16)(0.6f * ay);
        a04[k].x = (_Float16)(0.4f * ax); a04[k].y = (_Float16)(0.4f * ay);
    }

    f32x2 acc2[3] = {{0.f, 0.f}, {0.f, 0.f}, {0.f, 0.f}};
    float den_l = 0.f;

    const unsigned start = offs[wid];
    const int totalE = (int)(offs[wid + 1] - start) + 1;   // + self loop (k==0)
    const char* basep = (const char*)xlh;

    // prefetch chunk 0's source index
    int idv = wid;                                          // self-loop & filler
    {
        int k = lane;
        if (lane < CH && k > 0 && k < totalE) idv = csr_src[start + k - 1];
    }

    for (int base = 0; base < totalE; base += CH) {
        int rowb = idv * (C_DIM * 2);
        int ro[CH];
        #pragma unroll
        for (int tt = 0; tt < CH; ++tt) ro[tt] = __shfl(rowb, tt);

        unsigned pk0[CH], pk1[CH], pk2[CH];
        #pragma unroll
        for (int tt = 0; tt < CH; ++tt) {
            const char* p = basep + ro[tt] + byteoff;
            pk0[tt] = *(const unsigned*)(p);
            pk1[tt] = *(const unsigned*)(p + 256);
            pk2[tt] = 0u;
        }
        if (has2) {
            #pragma unroll
            for (int tt = 0; tt < CH; ++tt)
                pk2[tt] = *(const unsigned*)(basep + ro[tt] + byteoff + 512);
        }

        // issue next chunk's csr_src load now; lands during this chunk's compute
        idv = wid;
        {
            int k = base + CH + lane;
            if (lane < CH && k > 0 && k < totalE) idv = csr_src[start + k - 1];
        }

        #pragma unroll
        for (int tt = 0; tt < CH; ++tt) {
            h2 z0 = as_h2(pk0[tt]) + xr0;
            h2 z1 = as_h2(pk1[tt]) + xr1;
            h2 z2 = as_h2(pk2[tt]) + xr2;
            float p = fdot2w(z0, a06[0], 0.f);
            p = fdot2w(as_h2(as_u(z0) & 0x7FFF7FFFu), a04[0], p);
            p = fdot2w(z1, a06[1], p);
            p = fdot2w(as_h2(as_u(z1) & 0x7FFF7FFFu), a04[1], p);
            p = fdot2w(z2, a06[2], p);
            p = fdot2w(as_h2(as_u(z2) & 0x7FFF7FFFu), a04[2], p);
            part[tt * 68 + lane] = p;
        }

        float wgt;
        {
            const int oo = (o + t8) & 7;
            const float* rp = part + t8 * 68 + oo * 8;
            float4 s0 = *(const float4*)(rp + 0);
            float4 s1 = *(const float4*)(rp + 4);
            float e = ((s0.x + s0.y) + (s0.z + s0.w)) + ((s1.x + s1.y) + (s1.z + s1.w));
            e += __shfl_xor(e, 8);
            e += __shfl_xor(e, 16);
            e += __shfl_xor(e, 32);
            bool valid = (base + t8) < totalE;
            wgt = valid ? __expf(fminf(e, 60.f)) : 0.f;
        }

        den_l += wgt;

        _Float16 wh = (_Float16)wgt;
        h2 wpair = {wh, wh};
        unsigned wbits = as_u(wpair);
        h2 hacc0 = {(_Float16)0, (_Float16)0};
        h2 hacc1 = {(_Float16)0, (_Float16)0};
        h2 hacc2 = {(_Float16)0, (_Float16)0};
        #pragma unroll
        for (int tt = 0; tt < CH; ++tt) {
            h2 wt2 = as_h2(__shfl(wbits, tt));
            hacc0 += wt2 * as_h2(pk0[tt]);    // v_pk_fma_f16
            hacc1 += wt2 * as_h2(pk1[tt]);
            hacc2 += wt2 * as_h2(pk2[tt]);
        }
        acc2[0] += upv(as_u(hacc0));
        acc2[1] += upv(as_u(hacc1));
        acc2[2] += upv(as_u(hacc2));
    }

    float den = den_l;
    den += __shfl_xor(den, 1);
    den += __shfl_xor(den, 2);
    den += __shfl_xor(den, 4);

    const float invd = 1.f / den;
    float dot = 0.f;
    #pragma unroll
    for (int k = 0; k < 3; ++k) {
        #pragma unroll
        for (int j = 0; j < 2; ++j) {
            int c = 128 * k + l2 + j;
            float b = (c < C_DIM) ? bias[c] : 0.f;
            float l = (c < C_DIM) ? lw[c] : 0.f;
            float a = (j == 0) ? acc2[k].x : acc2[k].y;
            float h = fmaf(a, invd, b);
            h = h > 0.f ? h : 0.f;
            dot = fmaf(h, l, dot);
        }
    }
    #pragma unroll
    for (int off = 32; off; off >>= 1) dot += __shfl_xor(dot, off);
    if (lane == 0) y[wid] = 1.f / (1.f + __expf(-(dot + lb[0])));
}

extern "C" void kernel_launch(void* const* d_in, const int* in_sizes, int n_in,
                              void* d_out, int out_size, void* d_ws, size_t ws_size,
                              hipStream_t stream)
{
    const float* x    = (const float*)d_in[0];
    const int*   ei   = (const int*)d_in[1];
    const float* Wl   = (const float*)d_in[2];
    const float* bl   = (const float*)d_in[3];
    const float* Wr   = (const float*)d_in[4];
    const float* br   = (const float*)d_in[5];
    const float* att  = (const float*)d_in[6];
    const float* bias = (const float*)d_in[7];
    const float* lw   = (const float*)d_in[8];
    const float* lb   = (const float*)d_in[9];
    float* y = (float*)d_out;

    const int n  = in_sizes[0] / F_IN;   // 50000
    const int nE = in_sizes[1] / 2;      // 800000
    const int* src_arr = ei;
    const int* dst_arr = ei + nE;

    const int NB     = (n + 255) >> 8;            // 196 buckets
    const int total4 = (nE + 3) >> 2;             // int4 edge units
    const int chunk4 = (total4 + NPB - 1) / NPB;  // int4 units per block
    const int M      = 256 * NPB;                 // 65536 matrix entries

    // ws: xlh | xrh | Bp | bcnt(M) | boff(M+1) | offs(n+1) | csr_src(nE) | ebuf(nE)
    _Float16* xlh      = (_Float16*)d_ws;
    _Float16* xrh      = xlh + (size_t)n * C_DIM;
    _Float16* Bp       = xrh + (size_t)n * C_DIM;
    unsigned* bcnt     = (unsigned*)(Bp + NCT * 4 * 64 * 8);
    unsigned* boff     = bcnt + M;
    unsigned* offs     = boff + (M + 1);
    int*      csr_src  = (int*)(offs + (n + 1));
    unsigned* ebuf     = (unsigned*)(csr_src + nE);

    conv_count<<<NPB, 512, 0, stream>>>(Wl, Wr, Bp, dst_arr, bcnt, nE, chunk4);
    scan_all<<<1, 1024, 0, stream>>>(bcnt, boff, M);
    partition_edges<<<NPB, 512, 0, stream>>>(src_arr, dst_arr, boff, ebuf, nE, chunk4);
    bucket_csr<<<NB, 512, 0, stream>>>(ebuf, boff, offs, csr_src, n, nE, NB);

    gemm_xlxr<<<((n + 63) / 64) * 4, 256, 0, stream>>>(x, Bp, bl, br, xlh, xrh, n);

    gat_gather<<<(n + 3) / 4, 256, 0, stream>>>(csr_src, offs, xlh, xrh, att, bias, lw, lb, y, n);
}

// Round 11
// 239.783 us; speedup vs baseline: 1.0243x; 1.0243x over previous
//
#include <hip/hip_runtime.h>
#include <hip/hip_fp16.h>

#define F_IN 128
#define C_DIM 300
#define NEG_SLOPE 0.2f
#define NCT  38           // col-tile count for Bp (608 cols: 0-299=L, 304-603=R, rest pad)
#define CTH  19           // col-tiles per gemm block (2-way column split — verified r7/r9)
#define CH   8            // edges per chunk in gat_gather
#define NPB  256          // blocks for bucket passes (and matrix stride)

typedef _Float16 half8 __attribute__((ext_vector_type(8)));
typedef _Float16 half4 __attribute__((ext_vector_type(4)));
typedef _Float16 h2    __attribute__((ext_vector_type(2)));
typedef float    f32x4 __attribute__((ext_vector_type(4)));
typedef float    f32x2 __attribute__((ext_vector_type(2)));

__device__ inline h2 as_h2(unsigned u) { union { unsigned u; h2 h; } c; c.u = u; return c.h; }
__device__ inline unsigned as_u(h2 h)  { union { unsigned u; h2 h; } c; c.h = h; return c.u; }
__device__ inline f32x2 upv(unsigned u) {
    h2 h = as_h2(u);
    f32x2 r; r.x = (float)h.x; r.y = (float)h.y; return r;
}

#if __has_builtin(__builtin_amdgcn_fdot2)
__device__ inline float fdot2w(h2 a, h2 b, float c) {
    return __builtin_amdgcn_fdot2(a, b, c, false);
}
#else
__device__ inline float fdot2w(h2 a, h2 b, float c) {
    return fmaf((float)a.y, (float)b.y, fmaf((float)a.x, (float)b.x, c));
}
#endif

// ---------- K0+P1 merged: convert_w + bucket_count (512 thr = 8 waves/CU) ----------
__global__ __launch_bounds__(512) void conv_count(
    const float* __restrict__ Wl, const float* __restrict__ Wr,
    _Float16* __restrict__ Bp,
    const int* __restrict__ dst, unsigned* __restrict__ bcnt, int nE, int chunk4)
{
    __shared__ unsigned cnt[256];
    const int b = blockIdx.x, t = threadIdx.x;

    // convert_w: 608*128 = 77824 elems over 131072 threads (single strided step)
    {
        int idx = b * 512 + t;
        if (idx < 608 * F_IN) {
            int nn = idx % 608;
            int k  = idx / 608;
            float v = 0.f;
            if (nn < 300)                   v = Wl[k * C_DIM + nn];
            else if (nn >= 304 && nn < 604) v = Wr[k * C_DIM + (nn - 304)];
            int ct = nn >> 4, n16 = nn & 15;
            int kr = k & 31,  ks  = k >> 5;
            int lane = ((kr >> 3) << 4) | n16;
            int j = k & 7;
            Bp[((((ct * 4 + ks) * 64) + lane) << 3) | j] = (_Float16)v;
        }
    }

    if (t < 256) cnt[t] = 0;
    __syncthreads();
    const int4* dst4 = reinterpret_cast<const int4*>(dst);
    const int total4 = (nE + 3) >> 2;
    const int lo = b * chunk4;
    const int hi = min(total4, lo + chunk4);
    for (int i = lo + t; i < hi; i += 512) {
        int4 d = dst4[i];
        int e = i * 4;
        if (e + 3 < nE) {
            atomicAdd(&cnt[d.x >> 8], 1u);
            atomicAdd(&cnt[d.y >> 8], 1u);
            atomicAdd(&cnt[d.z >> 8], 1u);
            atomicAdd(&cnt[d.w >> 8], 1u);
        } else {
            if (e < nE)     atomicAdd(&cnt[d.x >> 8], 1u);
            if (e + 1 < nE) atomicAdd(&cnt[d.y >> 8], 1u);
            if (e + 2 < nE) atomicAdd(&cnt[d.z >> 8], 1u);
        }
    }
    __syncthreads();
    if (t < 256) bcnt[t * NPB + b] = cnt[t];
}

// ---------- P2: exclusive scan of the full 65536-entry matrix in ONE block ----------
__global__ __launch_bounds__(1024) void scan_all(
    const unsigned* __restrict__ bcnt, unsigned* __restrict__ boff, int M)
{
    __shared__ unsigned s[1024];
    const int t = threadIdx.x;
    unsigned loc[64];
    unsigned sum = 0;
    const uint4* in4 = reinterpret_cast<const uint4*>(bcnt) + (size_t)t * 16;
    #pragma unroll
    for (int j = 0; j < 16; ++j) {
        uint4 v = in4[j];
        loc[j * 4 + 0] = v.x; loc[j * 4 + 1] = v.y;
        loc[j * 4 + 2] = v.z; loc[j * 4 + 3] = v.w;
        sum += v.x + v.y + v.z + v.w;
    }
    s[t] = sum;
    __syncthreads();
    for (int off = 1; off < 1024; off <<= 1) {
        unsigned u = (t >= off) ? s[t - off] : 0u;
        __syncthreads();
        if (t >= off) s[t] += u;
        __syncthreads();
    }
    unsigned run = (t > 0) ? s[t - 1] : 0u;
    uint4* out4 = reinterpret_cast<uint4*>(boff) + (size_t)t * 16;
    #pragma unroll
    for (int j = 0; j < 16; ++j) {
        uint4 o;
        o.x = run; run += loc[j * 4 + 0];
        o.y = run; run += loc[j * 4 + 1];
        o.z = run; run += loc[j * 4 + 2];
        o.w = run; run += loc[j * 4 + 3];
        out4[j] = o;
    }
    if (t == 1023) boff[M] = run;
}

// P3: scatter edges into bucket-partitioned ebuf; packed u32/edge; int4 reads.
__global__ __launch_bounds__(512) void partition_edges(
    const int* __restrict__ src, const int* __restrict__ dst,
    const unsigned* __restrict__ boff,
    unsigned* __restrict__ ebuf, int nE, int chunk4)
{
    __shared__ unsigned cur[256];
    const int b = blockIdx.x, t = threadIdx.x;
    if (t < 256) cur[t] = boff[t * NPB + b];
    __syncthreads();
    const int4* dst4 = reinterpret_cast<const int4*>(dst);
    const int4* src4 = reinterpret_cast<const int4*>(src);
    const int total4 = (nE + 3) >> 2;
    const int lo = b * chunk4;
    const int hi = min(total4, lo + chunk4);
    for (int i = lo + t; i < hi; i += 512) {
        int4 d = dst4[i];
        int4 s = src4[i];
        int e = i * 4;
        int dv[4] = {d.x, d.y, d.z, d.w};
        int sv[4] = {s.x, s.y, s.z, s.w};
        #pragma unroll
        for (int j = 0; j < 4; ++j) {
            if (e + j < nE) {
                unsigned p = atomicAdd(&cur[dv[j] >> 8], 1u);
                ebuf[p] = (unsigned)sv[j] | ((unsigned)(dv[j] & 255) << 16);
            }
        }
    }
}

// P4: one block per bucket, 512 threads: LDS count + guarded LDS scan -> offs,
// LDS-cursor scatter.
__global__ __launch_bounds__(512) void bucket_csr(
    const unsigned* __restrict__ ebuf, const unsigned* __restrict__ boff,
    unsigned* __restrict__ offs, int* __restrict__ csr_src, int n, int nE, int nb)
{
    __shared__ unsigned cnt[256];
    __shared__ unsigned s[256];
    __shared__ unsigned cur[256];
    const int bk = blockIdx.x;
    const int t  = threadIdx.x;
    const unsigned bstart = boff[(unsigned)bk * NPB];
    const unsigned bend   = boff[(unsigned)(bk + 1) * NPB];
    if (t < 256) cnt[t] = 0;
    __syncthreads();
    for (unsigned i = bstart + t; i < bend; i += 512)
        atomicAdd(&cnt[(ebuf[i] >> 16) & 255], 1u);
    __syncthreads();
    unsigned v = (t < 256) ? cnt[t] : 0u;
    if (t < 256) s[t] = v;
    __syncthreads();
    for (int off = 1; off < 256; off <<= 1) {
        unsigned u = (t >= off && t < 256) ? s[t - off] : 0u;
        __syncthreads();
        if (t >= off && t < 256) s[t] += u;
        __syncthreads();
    }
    if (t < 256) {
        const unsigned excl = s[t] - v;
        const int node = (bk << 8) + t;
        if (node <= n) offs[node] = bstart + excl;
        cur[t] = bstart + excl;
    }
    if (t == 0 && bk == nb - 1 && (n & 255) == 0) offs[n] = (unsigned)nE;
    __syncthreads();
    for (unsigned i = bstart + t; i < bend; i += 512) {
        unsigned e = ebuf[i];
        unsigned p = atomicAdd(&cur[(e >> 16) & 255], 1u);
        csr_src[p] = (int)(e & 0xFFFFu);
    }
}

// ---------- K1: dual GEMM via f16 MFMA (round-7/9 verified structure) ----------
// 64-row blocks, 2-way column split (1564 blocks, 24 waves/CU) + next-ct B prefetch.
// Do NOT split further: 4-way (r10) doubled the fixed x-staging cost and regressed +20us.
__global__ __launch_bounds__(256) void gemm_xlxr(
    const float* __restrict__ x, const _Float16* __restrict__ Bp,
    const float* __restrict__ bl, const float* __restrict__ br,
    _Float16* __restrict__ xlh, _Float16* __restrict__ xrh, int n)
{
    __shared__ __align__(16) _Float16 xs[64][136];
    const int rg  = blockIdx.x >> 1;
    const int cs  = blockIdx.x & 1;
    const int rb0 = rg * 64;
    const int t   = threadIdx.x;

    #pragma unroll
    for (int i = 0; i < 8; ++i) {
        int flat = (i * 256 + t) * 4;
        int r = flat >> 7;
        int k = flat & 127;
        int gr = rb0 + r;
        if (gr >= n) gr = n - 1;
        float4 v = *reinterpret_cast<const float4*>(x + (size_t)gr * F_IN + k);
        half4 h = { (_Float16)v.x, (_Float16)v.y, (_Float16)v.z, (_Float16)v.w };
        *reinterpret_cast<half4*>(&xs[r][k]) = h;
    }
    __syncthreads();

    const int w    = t >> 6;
    const int lane = t & 63;
    const int m    = lane & 15;
    const int quad = lane >> 4;

    half8 a[4];
    #pragma unroll
    for (int ks = 0; ks < 4; ++ks)
        a[ks] = *reinterpret_cast<const half8*>(&xs[w * 16 + m][ks * 32 + quad * 8]);

    const int rbase = rb0 + w * 16 + quad * 4;
    const int ct0   = cs * CTH;

    const half8* bp = reinterpret_cast<const half8*>(Bp);
    half8 bc0 = bp[((size_t)(ct0 * 4 + 0) * 64) + lane];
    half8 bc1 = bp[((size_t)(ct0 * 4 + 1) * 64) + lane];
    half8 bc2 = bp[((size_t)(ct0 * 4 + 2) * 64) + lane];
    half8 bc3 = bp[((size_t)(ct0 * 4 + 3) * 64) + lane];

    for (int ci = 0; ci < CTH; ++ci) {
        const int ct  = ct0 + ci;
        const int ctn = (ci < CTH - 1) ? ct + 1 : ct;
        half8 bn0 = bp[((size_t)(ctn * 4 + 0) * 64) + lane];
        half8 bn1 = bp[((size_t)(ctn * 4 + 1) * 64) + lane];
        half8 bn2 = bp[((size_t)(ctn * 4 + 2) * 64) + lane];
        half8 bn3 = bp[((size_t)(ctn * 4 + 3) * 64) + lane];

        f32x4 acc = {0.f, 0.f, 0.f, 0.f};
        acc = __builtin_amdgcn_mfma_f32_16x16x32_f16(a[0], bc0, acc, 0, 0, 0);
        acc = __builtin_amdgcn_mfma_f32_16x16x32_f16(a[1], bc1, acc, 0, 0, 0);
        acc = __builtin_amdgcn_mfma_f32_16x16x32_f16(a[2], bc2, acc, 0, 0, 0);
        acc = __builtin_amdgcn_mfma_f32_16x16x32_f16(a[3], bc3, acc, 0, 0, 0);

        int col = ct * 16 + m;
        int isL = (col < 300);
        int isR = (col >= 304 && col < 604);
        if (isL | isR) {
            float bv = isL ? bl[col] : br[col - 304];
            _Float16* tab = isL ? (xlh + col) : (xrh + (col - 304));
            #pragma unroll
            for (int reg = 0; reg < 4; ++reg) {
                int row = rbase + reg;
                if (row < n)
                    tab[(size_t)row * C_DIM] = (_Float16)(acc[reg] + bv);
            }
        }
        bc0 = bn0; bc1 = bn1; bc2 = bn2; bc3 = bn3;
    }
}

// ---------- K2: fused per-node gather, chunked softmax (8 edges/iter) ----------
// 44-VGPR structure + next-chunk csr_src prefetch. FROZEN (rounds 2/4/5/7/9/10).
__global__ __launch_bounds__(256) void gat_gather(
    const int* __restrict__ csr_src, const unsigned* __restrict__ offs,
    const _Float16* __restrict__ xlh, const _Float16* __restrict__ xrh,
    const float* __restrict__ att, const float* __restrict__ bias,
    const float* __restrict__ lw, const float* __restrict__ lb,
    float* __restrict__ y, int n)
{
    __shared__ __align__(16) float lds[4 * 560];   // per wave: part[8][68]
    float* part = lds + (threadIdx.x >> 6) * 560;

    const int wid  = (blockIdx.x * blockDim.x + threadIdx.x) >> 6;
    const int lane = threadIdx.x & 63;
    if (wid >= n) return;

    const int l2   = 2 * lane;
    const bool has2 = (lane < 22);
    const int t8   = lane & 7;
    const int o    = lane >> 3;
    const int byteoff = lane * 4;

    const _Float16* xrrow = xrh + (size_t)wid * C_DIM;
    h2 xr0 = *(const h2*)(xrrow + l2);
    h2 xr1 = *(const h2*)(xrrow + 128 + l2);
    h2 xr2 = {(_Float16)0, (_Float16)0};
    if (has2) xr2 = *(const h2*)(xrrow + 256 + l2);

    h2 a06[3], a04[3];
    #pragma unroll
    for (int k = 0; k < 3; ++k) {
        int c = 128 * k + l2;
        float ax = (c < C_DIM) ? att[c] : 0.f;
        float ay = (c + 1 < C_DIM) ? att[c + 1] : 0.f;
        a06[k].x = (_Float16)(0.6f * ax); a06[k].y = (_Float16)(0.6f * ay);
        a04[k].x = (_Float16)(0.4f * ax); a04[k].y = (_Float16)(0.4f * ay);
    }

    f32x2 acc2[3] = {{0.f, 0.f}, {0.f, 0.f}, {0.f, 0.f}};
    float den_l = 0.f;

    const unsigned start = offs[wid];
    const int totalE = (int)(offs[wid + 1] - start) + 1;   // + self loop (k==0)
    const char* basep = (const char*)xlh;

    // prefetch chunk 0's source index
    int idv = wid;                                          // self-loop & filler
    {
        int k = lane;
        if (lane < CH && k > 0 && k < totalE) idv = csr_src[start + k - 1];
    }

    for (int base = 0; base < totalE; base += CH) {
        int rowb = idv * (C_DIM * 2);
        int ro[CH];
        #pragma unroll
        for (int tt = 0; tt < CH; ++tt) ro[tt] = __shfl(rowb, tt);

        unsigned pk0[CH], pk1[CH], pk2[CH];
        #pragma unroll
        for (int tt = 0; tt < CH; ++tt) {
            const char* p = basep + ro[tt] + byteoff;
            pk0[tt] = *(const unsigned*)(p);
            pk1[tt] = *(const unsigned*)(p + 256);
            pk2[tt] = 0u;
        }
        if (has2) {
            #pragma unroll
            for (int tt = 0; tt < CH; ++tt)
                pk2[tt] = *(const unsigned*)(basep + ro[tt] + byteoff + 512);
        }

        // issue next chunk's csr_src load now; lands during this chunk's compute
        idv = wid;
        {
            int k = base + CH + lane;
            if (lane < CH && k > 0 && k < totalE) idv = csr_src[start + k - 1];
        }

        #pragma unroll
        for (int tt = 0; tt < CH; ++tt) {
            h2 z0 = as_h2(pk0[tt]) + xr0;
            h2 z1 = as_h2(pk1[tt]) + xr1;
            h2 z2 = as_h2(pk2[tt]) + xr2;
            float p = fdot2w(z0, a06[0], 0.f);
            p = fdot2w(as_h2(as_u(z0) & 0x7FFF7FFFu), a04[0], p);
            p = fdot2w(z1, a06[1], p);
            p = fdot2w(as_h2(as_u(z1) & 0x7FFF7FFFu), a04[1], p);
            p = fdot2w(z2, a06[2], p);
            p = fdot2w(as_h2(as_u(z2) & 0x7FFF7FFFu), a04[2], p);
            part[tt * 68 + lane] = p;
        }

        float wgt;
        {
            const int oo = (o + t8) & 7;
            const float* rp = part + t8 * 68 + oo * 8;
            float4 s0 = *(const float4*)(rp + 0);
            float4 s1 = *(const float4*)(rp + 4);
            float e = ((s0.x + s0.y) + (s0.z + s0.w)) + ((s1.x + s1.y) + (s1.z + s1.w));
            e += __shfl_xor(e, 8);
            e += __shfl_xor(e, 16);
            e += __shfl_xor(e, 32);
            bool valid = (base + t8) < totalE;
            wgt = valid ? __expf(fminf(e, 60.f)) : 0.f;
        }

        den_l += wgt;

        _Float16 wh = (_Float16)wgt;
        h2 wpair = {wh, wh};
        unsigned wbits = as_u(wpair);
        h2 hacc0 = {(_Float16)0, (_Float16)0};
        h2 hacc1 = {(_Float16)0, (_Float16)0};
        h2 hacc2 = {(_Float16)0, (_Float16)0};
        #pragma unroll
        for (int tt = 0; tt < CH; ++tt) {
            h2 wt2 = as_h2(__shfl(wbits, tt));
            hacc0 += wt2 * as_h2(pk0[tt]);    // v_pk_fma_f16
            hacc1 += wt2 * as_h2(pk1[tt]);
            hacc2 += wt2 * as_h2(pk2[tt]);
        }
        acc2[0] += upv(as_u(hacc0));
        acc2[1] += upv(as_u(hacc1));
        acc2[2] += upv(as_u(hacc2));
    }

    float den = den_l;
    den += __shfl_xor(den, 1);
    den += __shfl_xor(den, 2);
    den += __shfl_xor(den, 4);

    const float invd = 1.f / den;
    float dot = 0.f;
    #pragma unroll
    for (int k = 0; k < 3; ++k) {
        #pragma unroll
        for (int j = 0; j < 2; ++j) {
            int c = 128 * k + l2 + j;
            float b = (c < C_DIM) ? bias[c] : 0.f;
            float l = (c < C_DIM) ? lw[c] : 0.f;
            float a = (j == 0) ? acc2[k].x : acc2[k].y;
            float h = fmaf(a, invd, b);
            h = h > 0.f ? h : 0.f;
            dot = fmaf(h, l, dot);
        }
    }
    #pragma unroll
    for (int off = 32; off; off >>= 1) dot += __shfl_xor(dot, off);
    if (lane == 0) y[wid] = 1.f / (1.f + __expf(-(dot + lb[0])));
}

extern "C" void kernel_launch(void* const* d_in, const int* in_sizes, int n_in,
                              void* d_out, int out_size, void* d_ws, size_t ws_size,
                              hipStream_t stream)
{
    const float* x    = (const float*)d_in[0];
    const int*   ei   = (const int*)d_in[1];
    const float* Wl   = (const float*)d_in[2];
    const float* bl   = (const float*)d_in[3];
    const float* Wr   = (const float*)d_in[4];
    const float* br   = (const float*)d_in[5];
    const float* att  = (const float*)d_in[6];
    const float* bias = (const float*)d_in[7];
    const float* lw   = (const float*)d_in[8];
    const float* lb   = (const float*)d_in[9];
    float* y = (float*)d_out;

    const int n  = in_sizes[0] / F_IN;   // 50000
    const int nE = in_sizes[1] / 2;      // 800000
    const int* src_arr = ei;
    const int* dst_arr = ei + nE;

    const int NB     = (n + 255) >> 8;            // 196 buckets
    const int total4 = (nE + 3) >> 2;             // int4 edge units
    const int chunk4 = (total4 + NPB - 1) / NPB;  // int4 units per block
    const int M      = 256 * NPB;                 // 65536 matrix entries

    // ws: xlh | xrh | Bp | bcnt(M) | boff(M+1) | offs(n+1) | csr_src(nE) | ebuf(nE)
    _Float16* xlh      = (_Float16*)d_ws;
    _Float16* xrh      = xlh + (size_t)n * C_DIM;
    _Float16* Bp       = xrh + (size_t)n * C_DIM;
    unsigned* bcnt     = (unsigned*)(Bp + NCT * 4 * 64 * 8);
    unsigned* boff     = bcnt + M;
    unsigned* offs     = boff + (M + 1);
    int*      csr_src  = (int*)(offs + (n + 1));
    unsigned* ebuf     = (unsigned*)(csr_src + nE);

    conv_count<<<NPB, 512, 0, stream>>>(Wl, Wr, Bp, dst_arr, bcnt, nE, chunk4);
    scan_all<<<1, 1024, 0, stream>>>(bcnt, boff, M);
    partition_edges<<<NPB, 512, 0, stream>>>(src_arr, dst_arr, boff, ebuf, nE, chunk4);
    bucket_csr<<<NB, 512, 0, stream>>>(ebuf, boff, offs, csr_src, n, nE, NB);

    gemm_xlxr<<<((n + 63) / 64) * 2, 256, 0, stream>>>(x, Bp, bl, br, xlh, xrh, n);

    gat_gather<<<(n + 3) / 4, 256, 0, stream>>>(csr_src, offs, xlh, xrh, att, bias, lw, lb, y, n);
}

// Round 12
// 223.587 us; speedup vs baseline: 1.0985x; 1.0724x over previous
//
#include <hip/hip_runtime.h>
#include <hip/hip_fp16.h>

#define F_IN 128
#define C_DIM 300
#define NEG_SLOPE 0.2f
#define NCT  38           // col-tile count for Bp (608 cols: 0-299=L, 304-603=R, rest pad)
#define CTH  19           // col-tiles per gemm block (2-way column split — verified r7/r9)
#define CH   8            // edges per chunk in gat_gather
#define NPB  256          // blocks for bucket passes (and matrix stride)

typedef _Float16 half8 __attribute__((ext_vector_type(8)));
typedef _Float16 half4 __attribute__((ext_vector_type(4)));
typedef _Float16 h2    __attribute__((ext_vector_type(2)));
typedef float    f32x4 __attribute__((ext_vector_type(4)));
typedef float    f32x2 __attribute__((ext_vector_type(2)));

__device__ inline h2 as_h2(unsigned u) { union { unsigned u; h2 h; } c; c.u = u; return c.h; }
__device__ inline unsigned as_u(h2 h)  { union { unsigned u; h2 h; } c; c.h = h; return c.u; }
__device__ inline f32x2 upv(unsigned u) {
    h2 h = as_h2(u);
    f32x2 r; r.x = (float)h.x; r.y = (float)h.y; return r;
}

#if __has_builtin(__builtin_amdgcn_fdot2)
__device__ inline float fdot2w(h2 a, h2 b, float c) {
    return __builtin_amdgcn_fdot2(a, b, c, false);
}
#else
__device__ inline float fdot2w(h2 a, h2 b, float c) {
    return fmaf((float)a.y, (float)b.y, fmaf((float)a.x, (float)b.x, c));
}
#endif

// ---------- K0+P1 merged: convert_w + bucket_count (512 thr = 8 waves/CU) ----------
__global__ __launch_bounds__(512) void conv_count(
    const float* __restrict__ Wl, const float* __restrict__ Wr,
    _Float16* __restrict__ Bp,
    const int* __restrict__ dst, unsigned* __restrict__ bcnt, int nE, int chunk4)
{
    __shared__ unsigned cnt[256];
    const int b = blockIdx.x, t = threadIdx.x;

    // convert_w: 608*128 = 77824 elems over 131072 threads (single strided step)
    {
        int idx = b * 512 + t;
        if (idx < 608 * F_IN) {
            int nn = idx % 608;
            int k  = idx / 608;
            float v = 0.f;
            if (nn < 300)                   v = Wl[k * C_DIM + nn];
            else if (nn >= 304 && nn < 604) v = Wr[k * C_DIM + (nn - 304)];
            int ct = nn >> 4, n16 = nn & 15;
            int kr = k & 31,  ks  = k >> 5;
            int lane = ((kr >> 3) << 4) | n16;
            int j = k & 7;
            Bp[((((ct * 4 + ks) * 64) + lane) << 3) | j] = (_Float16)v;
        }
    }

    if (t < 256) cnt[t] = 0;
    __syncthreads();
    const int4* dst4 = reinterpret_cast<const int4*>(dst);
    const int total4 = (nE + 3) >> 2;
    const int lo = b * chunk4;
    const int hi = min(total4, lo + chunk4);
    for (int i = lo + t; i < hi; i += 512) {
        int4 d = dst4[i];
        int e = i * 4;
        if (e + 3 < nE) {
            atomicAdd(&cnt[d.x >> 8], 1u);
            atomicAdd(&cnt[d.y >> 8], 1u);
            atomicAdd(&cnt[d.z >> 8], 1u);
            atomicAdd(&cnt[d.w >> 8], 1u);
        } else {
            if (e < nE)     atomicAdd(&cnt[d.x >> 8], 1u);
            if (e + 1 < nE) atomicAdd(&cnt[d.y >> 8], 1u);
            if (e + 2 < nE) atomicAdd(&cnt[d.z >> 8], 1u);
        }
    }
    __syncthreads();
    if (t < 256) bcnt[t * NPB + b] = cnt[t];
}

__global__ __launch_bounds__(256) void scan_part(
    const unsigned* __restrict__ counts, unsigned* __restrict__ bsum, int n)
{
    __shared__ unsigned s[256];
    const int t = threadIdx.x;
    const int base = blockIdx.x * 1024 + t * 4;
    unsigned v = 0;
    #pragma unroll
    for (int i = 0; i < 4; ++i) {
        int idx = base + i;
        if (idx < n) v += counts[idx];
    }
    s[t] = v;
    __syncthreads();
    for (int off = 128; off > 0; off >>= 1) {
        if (t < off) s[t] += s[t + off];
        __syncthreads();
    }
    if (t == 0) bsum[blockIdx.x] = s[0];
}

// scan_final with scan_mid folded in: wave 0 recomputes the 64-wide block-prefix
__global__ __launch_bounds__(256) void scan_final(
    const unsigned* __restrict__ counts, const unsigned* __restrict__ bsum,
    unsigned* __restrict__ offs, int n, int nblk)
{
    __shared__ unsigned s[256];
    __shared__ unsigned sbase;
    const int t = threadIdx.x;
    if (t < 64) {
        unsigned v64 = (t < nblk) ? bsum[t] : 0u;
        unsigned inc = v64;
        #pragma unroll
        for (int off = 1; off < 64; off <<= 1) {
            unsigned u = __shfl_up(inc, off);
            if (t >= off) inc += u;
        }
        if (t == (int)blockIdx.x) sbase = inc - v64;   // exclusive prefix for this block
        if (blockIdx.x == gridDim.x - 1 && t == 63) offs[n] = inc;  // grand total
    }
    const int base = blockIdx.x * 1024 + t * 4;
    unsigned c[4];
    unsigned v = 0;
    #pragma unroll
    for (int i = 0; i < 4; ++i) {
        int idx = base + i;
        c[i] = (idx < n) ? counts[idx] : 0u;
        v += c[i];
    }
    s[t] = v;
    __syncthreads();
    for (int off = 1; off < 256; off <<= 1) {
        unsigned u = (t >= off) ? s[t - off] : 0u;
        __syncthreads();
        if (t >= off) s[t] += u;
        __syncthreads();
    }
    unsigned run = sbase + s[t] - v;
    #pragma unroll
    for (int i = 0; i < 4; ++i) {
        int idx = base + i;
        if (idx < n) {
            offs[idx] = run;
            run += c[i];
        }
    }
}

// P3: scatter edges into bucket-partitioned ebuf; packed u32/edge; int4 reads.
__global__ __launch_bounds__(512) void partition_edges(
    const int* __restrict__ src, const int* __restrict__ dst,
    const unsigned* __restrict__ boff,
    unsigned* __restrict__ ebuf, int nE, int chunk4)
{
    __shared__ unsigned cur[256];
    const int b = blockIdx.x, t = threadIdx.x;
    if (t < 256) cur[t] = boff[t * NPB + b];
    __syncthreads();
    const int4* dst4 = reinterpret_cast<const int4*>(dst);
    const int4* src4 = reinterpret_cast<const int4*>(src);
    const int total4 = (nE + 3) >> 2;
    const int lo = b * chunk4;
    const int hi = min(total4, lo + chunk4);
    for (int i = lo + t; i < hi; i += 512) {
        int4 d = dst4[i];
        int4 s = src4[i];
        int e = i * 4;
        int dv[4] = {d.x, d.y, d.z, d.w};
        int sv[4] = {s.x, s.y, s.z, s.w};
        #pragma unroll
        for (int j = 0; j < 4; ++j) {
            if (e + j < nE) {
                unsigned p = atomicAdd(&cur[dv[j] >> 8], 1u);
                ebuf[p] = (unsigned)sv[j] | ((unsigned)(dv[j] & 255) << 16);
            }
        }
    }
}

// P4: one block per bucket, 512 threads: LDS count + guarded LDS scan -> offs,
// LDS-cursor scatter.
__global__ __launch_bounds__(512) void bucket_csr(
    const unsigned* __restrict__ ebuf, const unsigned* __restrict__ boff,
    unsigned* __restrict__ offs, int* __restrict__ csr_src, int n, int nE, int nb)
{
    __shared__ unsigned cnt[256];
    __shared__ unsigned s[256];
    __shared__ unsigned cur[256];
    const int bk = blockIdx.x;
    const int t  = threadIdx.x;
    const unsigned bstart = boff[(unsigned)bk * NPB];
    const unsigned bend   = boff[(unsigned)(bk + 1) * NPB];
    if (t < 256) cnt[t] = 0;
    __syncthreads();
    for (unsigned i = bstart + t; i < bend; i += 512)
        atomicAdd(&cnt[(ebuf[i] >> 16) & 255], 1u);
    __syncthreads();
    unsigned v = (t < 256) ? cnt[t] : 0u;
    if (t < 256) s[t] = v;
    __syncthreads();
    for (int off = 1; off < 256; off <<= 1) {
        unsigned u = (t >= off && t < 256) ? s[t - off] : 0u;
        __syncthreads();
        if (t >= off && t < 256) s[t] += u;
        __syncthreads();
    }
    if (t < 256) {
        const unsigned excl = s[t] - v;
        const int node = (bk << 8) + t;
        if (node <= n) offs[node] = bstart + excl;
        cur[t] = bstart + excl;
    }
    if (t == 0 && bk == nb - 1 && (n & 255) == 0) offs[n] = (unsigned)nE;
    __syncthreads();
    for (unsigned i = bstart + t; i < bend; i += 512) {
        unsigned e = ebuf[i];
        unsigned p = atomicAdd(&cur[(e >> 16) & 255], 1u);
        csr_src[p] = (int)(e & 0xFFFFu);
    }
}

// ---------- K1: dual GEMM via f16 MFMA (round-7/9 verified structure) ----------
// 64-row blocks, 2-way column split (1564 blocks, 24 waves/CU) + next-ct B prefetch.
// Do NOT split further (4-way: +5.6us, r10/r11 decomposition) and do NOT grow the
// row-block (RB=128/256 regressed r1/r5 — occupancy is the lever on this workload).
__global__ __launch_bounds__(256) void gemm_xlxr(
    const float* __restrict__ x, const _Float16* __restrict__ Bp,
    const float* __restrict__ bl, const float* __restrict__ br,
    _Float16* __restrict__ xlh, _Float16* __restrict__ xrh, int n)
{
    __shared__ __align__(16) _Float16 xs[64][136];
    const int rg  = blockIdx.x >> 1;
    const int cs  = blockIdx.x & 1;
    const int rb0 = rg * 64;
    const int t   = threadIdx.x;

    #pragma unroll
    for (int i = 0; i < 8; ++i) {
        int flat = (i * 256 + t) * 4;
        int r = flat >> 7;
        int k = flat & 127;
        int gr = rb0 + r;
        if (gr >= n) gr = n - 1;
        float4 v = *reinterpret_cast<const float4*>(x + (size_t)gr * F_IN + k);
        half4 h = { (_Float16)v.x, (_Float16)v.y, (_Float16)v.z, (_Float16)v.w };
        *reinterpret_cast<half4*>(&xs[r][k]) = h;
    }
    __syncthreads();

    const int w    = t >> 6;
    const int lane = t & 63;
    const int m    = lane & 15;
    const int quad = lane >> 4;

    half8 a[4];
    #pragma unroll
    for (int ks = 0; ks < 4; ++ks)
        a[ks] = *reinterpret_cast<const half8*>(&xs[w * 16 + m][ks * 32 + quad * 8]);

    const int rbase = rb0 + w * 16 + quad * 4;
    const int ct0   = cs * CTH;

    const half8* bp = reinterpret_cast<const half8*>(Bp);
    half8 bc0 = bp[((size_t)(ct0 * 4 + 0) * 64) + lane];
    half8 bc1 = bp[((size_t)(ct0 * 4 + 1) * 64) + lane];
    half8 bc2 = bp[((size_t)(ct0 * 4 + 2) * 64) + lane];
    half8 bc3 = bp[((size_t)(ct0 * 4 + 3) * 64) + lane];

    for (int ci = 0; ci < CTH; ++ci) {
        const int ct  = ct0 + ci;
        const int ctn = (ci < CTH - 1) ? ct + 1 : ct;
        half8 bn0 = bp[((size_t)(ctn * 4 + 0) * 64) + lane];
        half8 bn1 = bp[((size_t)(ctn * 4 + 1) * 64) + lane];
        half8 bn2 = bp[((size_t)(ctn * 4 + 2) * 64) + lane];
        half8 bn3 = bp[((size_t)(ctn * 4 + 3) * 64) + lane];

        f32x4 acc = {0.f, 0.f, 0.f, 0.f};
        acc = __builtin_amdgcn_mfma_f32_16x16x32_f16(a[0], bc0, acc, 0, 0, 0);
        acc = __builtin_amdgcn_mfma_f32_16x16x32_f16(a[1], bc1, acc, 0, 0, 0);
        acc = __builtin_amdgcn_mfma_f32_16x16x32_f16(a[2], bc2, acc, 0, 0, 0);
        acc = __builtin_amdgcn_mfma_f32_16x16x32_f16(a[3], bc3, acc, 0, 0, 0);

        int col = ct * 16 + m;
        int isL = (col < 300);
        int isR = (col >= 304 && col < 604);
        if (isL | isR) {
            float bv = isL ? bl[col] : br[col - 304];
            _Float16* tab = isL ? (xlh + col) : (xrh + (col - 304));
            #pragma unroll
            for (int reg = 0; reg < 4; ++reg) {
                int row = rbase + reg;
                if (row < n)
                    tab[(size_t)row * C_DIM] = (_Float16)(acc[reg] + bv);
            }
        }
        bc0 = bn0; bc1 = bn1; bc2 = bn2; bc3 = bn3;
    }
}

// ---------- K2: fused per-node gather, chunked softmax (8 edges/iter) ----------
// 44-VGPR structure + next-chunk csr_src prefetch. FROZEN (rounds 2/4/5/7/9/10/11;
// at pattern-BW floor: ~276 MB @ ~3.2 TB/s).
__global__ __launch_bounds__(256) void gat_gather(
    const int* __restrict__ csr_src, const unsigned* __restrict__ offs,
    const _Float16* __restrict__ xlh, const _Float16* __restrict__ xrh,
    const float* __restrict__ att, const float* __restrict__ bias,
    const float* __restrict__ lw, const float* __restrict__ lb,
    float* __restrict__ y, int n)
{
    __shared__ __align__(16) float lds[4 * 560];   // per wave: part[8][68]
    float* part = lds + (threadIdx.x >> 6) * 560;

    const int wid  = (blockIdx.x * blockDim.x + threadIdx.x) >> 6;
    const int lane = threadIdx.x & 63;
    if (wid >= n) return;

    const int l2   = 2 * lane;
    const bool has2 = (lane < 22);
    const int t8   = lane & 7;
    const int o    = lane >> 3;
    const int byteoff = lane * 4;

    const _Float16* xrrow = xrh + (size_t)wid * C_DIM;
    h2 xr0 = *(const h2*)(xrrow + l2);
    h2 xr1 = *(const h2*)(xrrow + 128 + l2);
    h2 xr2 = {(_Float16)0, (_Float16)0};
    if (has2) xr2 = *(const h2*)(xrrow + 256 + l2);

    h2 a06[3], a04[3];
    #pragma unroll
    for (int k = 0; k < 3; ++k) {
        int c = 128 * k + l2;
        float ax = (c < C_DIM) ? att[c] : 0.f;
        float ay = (c + 1 < C_DIM) ? att[c + 1] : 0.f;
        a06[k].x = (_Float16)(0.6f * ax); a06[k].y = (_Float16)(0.6f * ay);
        a04[k].x = (_Float16)(0.4f * ax); a04[k].y = (_Float16)(0.4f * ay);
    }

    f32x2 acc2[3] = {{0.f, 0.f}, {0.f, 0.f}, {0.f, 0.f}};
    float den_l = 0.f;

    const unsigned start = offs[wid];
    const int totalE = (int)(offs[wid + 1] - start) + 1;   // + self loop (k==0)
    const char* basep = (const char*)xlh;

    // prefetch chunk 0's source index
    int idv = wid;                                          // self-loop & filler
    {
        int k = lane;
        if (lane < CH && k > 0 && k < totalE) idv = csr_src[start + k - 1];
    }

    for (int base = 0; base < totalE; base += CH) {
        int rowb = idv * (C_DIM * 2);
        int ro[CH];
        #pragma unroll
        for (int tt = 0; tt < CH; ++tt) ro[tt] = __shfl(rowb, tt);

        unsigned pk0[CH], pk1[CH], pk2[CH];
        #pragma unroll
        for (int tt = 0; tt < CH; ++tt) {
            const char* p = basep + ro[tt] + byteoff;
            pk0[tt] = *(const unsigned*)(p);
            pk1[tt] = *(const unsigned*)(p + 256);
            pk2[tt] = 0u;
        }
        if (has2) {
            #pragma unroll
            for (int tt = 0; tt < CH; ++tt)
                pk2[tt] = *(const unsigned*)(basep + ro[tt] + byteoff + 512);
        }

        // issue next chunk's csr_src load now; lands during this chunk's compute
        idv = wid;
        {
            int k = base + CH + lane;
            if (lane < CH && k > 0 && k < totalE) idv = csr_src[start + k - 1];
        }

        #pragma unroll
        for (int tt = 0; tt < CH; ++tt) {
            h2 z0 = as_h2(pk0[tt]) + xr0;
            h2 z1 = as_h2(pk1[tt]) + xr1;
            h2 z2 = as_h2(pk2[tt]) + xr2;
            float p = fdot2w(z0, a06[0], 0.f);
            p = fdot2w(as_h2(as_u(z0) & 0x7FFF7FFFu), a04[0], p);
            p = fdot2w(z1, a06[1], p);
            p = fdot2w(as_h2(as_u(z1) & 0x7FFF7FFFu), a04[1], p);
            p = fdot2w(z2, a06[2], p);
            p = fdot2w(as_h2(as_u(z2) & 0x7FFF7FFFu), a04[2], p);
            part[tt * 68 + lane] = p;
        }

        float wgt;
        {
            const int oo = (o + t8) & 7;
            const float* rp = part + t8 * 68 + oo * 8;
            float4 s0 = *(const float4*)(rp + 0);
            float4 s1 = *(const float4*)(rp + 4);
            float e = ((s0.x + s0.y) + (s0.z + s0.w)) + ((s1.x + s1.y) + (s1.z + s1.w));
            e += __shfl_xor(e, 8);
            e += __shfl_xor(e, 16);
            e += __shfl_xor(e, 32);
            bool valid = (base + t8) < totalE;
            wgt = valid ? __expf(fminf(e, 60.f)) : 0.f;
        }

        den_l += wgt;

        _Float16 wh = (_Float16)wgt;
        h2 wpair = {wh, wh};
        unsigned wbits = as_u(wpair);
        h2 hacc0 = {(_Float16)0, (_Float16)0};
        h2 hacc1 = {(_Float16)0, (_Float16)0};
        h2 hacc2 = {(_Float16)0, (_Float16)0};
        #pragma unroll
        for (int tt = 0; tt < CH; ++tt) {
            h2 wt2 = as_h2(__shfl(wbits, tt));
            hacc0 += wt2 * as_h2(pk0[tt]);    // v_pk_fma_f16
            hacc1 += wt2 * as_h2(pk1[tt]);
            hacc2 += wt2 * as_h2(pk2[tt]);
        }
        acc2[0] += upv(as_u(hacc0));
        acc2[1] += upv(as_u(hacc1));
        acc2[2] += upv(as_u(hacc2));
    }

    float den = den_l;
    den += __shfl_xor(den, 1);
    den += __shfl_xor(den, 2);
    den += __shfl_xor(den, 4);

    const float invd = 1.f / den;
    float dot = 0.f;
    #pragma unroll
    for (int k = 0; k < 3; ++k) {
        #pragma unroll
        for (int j = 0; j < 2; ++j) {
            int c = 128 * k + l2 + j;
            float b = (c < C_DIM) ? bias[c] : 0.f;
            float l = (c < C_DIM) ? lw[c] : 0.f;
            float a = (j == 0) ? acc2[k].x : acc2[k].y;
            float h = fmaf(a, invd, b);
            h = h > 0.f ? h : 0.f;
            dot = fmaf(h, l, dot);
        }
    }
    #pragma unroll
    for (int off = 32; off; off >>= 1) dot += __shfl_xor(dot, off);
    if (lane == 0) y[wid] = 1.f / (1.f + __expf(-(dot + lb[0])));
}

extern "C" void kernel_launch(void* const* d_in, const int* in_sizes, int n_in,
                              void* d_out, int out_size, void* d_ws, size_t ws_size,
                              hipStream_t stream)
{
    const float* x    = (const float*)d_in[0];
    const int*   ei   = (const int*)d_in[1];
    const float* Wl   = (const float*)d_in[2];
    const float* bl   = (const float*)d_in[3];
    const float* Wr   = (const float*)d_in[4];
    const float* br   = (const float*)d_in[5];
    const float* att  = (const float*)d_in[6];
    const float* bias = (const float*)d_in[7];
    const float* lw   = (const float*)d_in[8];
    const float* lb   = (const float*)d_in[9];
    float* y = (float*)d_out;

    const int n  = in_sizes[0] / F_IN;   // 50000
    const int nE = in_sizes[1] / 2;      // 800000
    const int* src_arr = ei;
    const int* dst_arr = ei + nE;

    const int NB     = (n + 255) >> 8;            // 196 buckets
    const int total4 = (nE + 3) >> 2;             // int4 edge units
    const int chunk4 = (total4 + NPB - 1) / NPB;  // int4 units per block
    const int M      = 256 * NPB;                 // 65536 matrix entries
    const int nblkM  = (M + 1023) / 1024;         // 64

    // ws: xlh | xrh | Bp | bcnt(M) | boff(M+1) | offs(n+1) | bsum(64)
    //     | csr_src(nE) | ebuf(nE)
    _Float16* xlh      = (_Float16*)d_ws;
    _Float16* xrh      = xlh + (size_t)n * C_DIM;
    _Float16* Bp       = xrh + (size_t)n * C_DIM;
    unsigned* bcnt     = (unsigned*)(Bp + NCT * 4 * 64 * 8);
    unsigned* boff     = bcnt + M;
    unsigned* offs     = boff + (M + 1);
    unsigned* bsum     = offs + (n + 1);
    int*      csr_src  = (int*)(bsum + 64);
    unsigned* ebuf     = (unsigned*)(csr_src + nE);

    conv_count<<<NPB, 512, 0, stream>>>(Wl, Wr, Bp, dst_arr, bcnt, nE, chunk4);
    scan_part<<<nblkM, 256, 0, stream>>>(bcnt, bsum, M);
    scan_final<<<nblkM, 256, 0, stream>>>(bcnt, bsum, boff, M, nblkM);
    partition_edges<<<NPB, 512, 0, stream>>>(src_arr, dst_arr, boff, ebuf, nE, chunk4);
    bucket_csr<<<NB, 512, 0, stream>>>(ebuf, boff, offs, csr_src, n, nE, NB);

    gemm_xlxr<<<((n + 63) / 64) * 2, 256, 0, stream>>>(x, Bp, bl, br, xlh, xrh, n);

    gat_gather<<<(n + 3) / 4, 256, 0, stream>>>(csr_src, offs, xlh, xrh, att, bias, lw, lb, y, n);
}